// Round 11
// baseline (249.258 us; speedup 1.0000x reference)
//
#include <hip/hip_runtime.h>
#include <hip/hip_bf16.h>
#include <math.h>

#define LHIST 50

typedef __attribute__((ext_vector_type(8))) short bf16x8;
typedef __attribute__((ext_vector_type(4))) float f32x4;

__device__ __forceinline__ unsigned short f2bf(float f) {
    union { float f; unsigned u; } v; v.f = f;
    unsigned r = v.u + 0x7fff + ((v.u >> 16) & 1);   // RNE
    return (unsigned short)(r >> 16);
}
__device__ __forceinline__ unsigned pk2(float lo, float hi) {   // v_cvt_pk_bf16_f32
    __hip_bfloat162 h = __float22bfloat162_rn(make_float2(lo, hi));
    return *(unsigned*)&h;
}

// ws float offsets:
//  Awt    [80][64] fp32                   @ 0         (5120)
//  Bmf32  frag fp32 [nt5][ks2][lane][8]   @ 5120      (5120)
//  W4f32  frag fp32 [nt5][ks2][lane][8]   @ 10240     (5120)
//  W1f    frag bf16 [nt16][ks5][lane][8]  @ 15360     (20480 f)
//  W2f    frag bf16 [nt8][ks8][lane][8]   @ 35840     (16384 f)
//  combined [B][160] fp32                 @ 52224

__global__ void prep_kernel(const float* __restrict__ aw1,
                            const float* __restrict__ mw1,
                            const float* __restrict__ mw2,
                            float* __restrict__ Awt,
                            float* __restrict__ Bmf32,
                            float* __restrict__ W4f32,
                            unsigned short* __restrict__ W1f,
                            unsigned short* __restrict__ W2f) {
    int i = blockIdx.x * 256 + threadIdx.x;
    if (i < 5120) {
        int j = i >> 6, k = i & 63;
        Awt[i] = aw1[k * 80 + j] + aw1[(128 + k) * 80 + j];     // (W1+W3)^T
        int kk = i / 80, n = i - kk * 80;
        int nt = n >> 4, colw = n & 15, ks = kk >> 5, r = kk & 31, qd = r >> 3, off = r & 7;
        int d = ((nt * 2 + ks) * 64 + qd * 16 + colw) * 8 + off;
        Bmf32[d] = aw1[(64 + kk) * 80 + n] - aw1[(128 + kk) * 80 + n];  // W2-W3
        W4f32[d] = aw1[(192 + kk) * 80 + n];
    }
    if (i < 40960) {
        int kk = i >> 8, n = i & 255;
        int nt = n >> 4, colw = n & 15, ks = kk >> 5, r = kk & 31, qd = r >> 3, off = r & 7;
        W1f[((nt * 5 + ks) * 64 + qd * 16 + colw) * 8 + off] = f2bf(mw1[i]);
    }
    if (i < 32768) {
        int kk = i >> 7, n = i & 127;
        int nt = n >> 4, colw = n & 15, ks = kk >> 5, r = kk & 31, qd = r >> 3, off = r & 7;
        W2f[((nt * 8 + ks) * 64 + qd * 16 + colw) * 8 + off] = f2bf(mw2[i]);
    }
}

// ---------- attention: 2 batches/block, transposed MFMA, fp32 direct gathers ----------
__global__ void __launch_bounds__(256, 6) attn_kernel(
    const int* __restrict__ cid, const int* __restrict__ cg,
    const int* __restrict__ cc,  const int* __restrict__ hg,
    const int* __restrict__ hc,
    const float* __restrict__ user_table, const float* __restrict__ item_table,
    const float* __restrict__ cat_table,
    const float* __restrict__ ab1, const float* __restrict__ aw2,
    const float* __restrict__ Awt, const float* __restrict__ Bmf32,
    const float* __restrict__ W4f32,
    float* __restrict__ combined)
{
    __shared__ __align__(16) unsigned short sh_Bq[2][5120];   // [b][nt5][ks2][lane][8]; reused as att scratch
    __shared__ __align__(16) float sh_q[2][64];
    __shared__ float sh_bias[2][80];
    __shared__ float sh_sc[2][64];
    __shared__ float sh_aw2[80];
    __shared__ float sh_att[4][64];

    const int t = threadIdx.x;
    const int b0 = blockIdx.x * 2;
    const int wv = t >> 6;
    const int lane = t & 63;
    const int quad = lane >> 4;
    const int col = lane & 15;
    const int bb = wv >> 1;      // batch of this wave
    const int hwv = wv & 1;      // half of l-range
    const int b = b0 + bb;

    // ---- P0: history indices + fp32 gathers issued immediately ----
    int il[2], ic[2];
    #pragma unroll
    for (int mi = 0; mi < 2; ++mi) {
        int l = hwv * 32 + mi * 16 + col;
        int lc = (l < LHIST) ? l : 0;
        il[mi] = hg[b * LHIST + lc];
        ic[mi] = hc[b * LHIST + lc];
    }
    float4 fi[2][2], fc[2][2];
    #pragma unroll
    for (int mi = 0; mi < 2; ++mi) {
        const float* ip = item_table + (size_t)il[mi] * 32 + quad * 8;
        const float* cp = cat_table  + (size_t)ic[mi] * 32 + quad * 8;
        fi[mi][0] = *(const float4*)ip;     fi[mi][1] = *(const float4*)(ip + 4);
        fc[mi][0] = *(const float4*)cp;     fc[mi][1] = *(const float4*)(cp + 4);
    }
    if (t < 128) {
        int qbi = t >> 6, k = t & 63;
        int bq = b0 + qbi;
        float v = (k < 32) ? item_table[(size_t)cg[bq] * 32 + k]
                           : cat_table[(size_t)cc[bq] * 32 + (k - 32)];
        sh_q[qbi][k] = v;
    }
    if (t < 80) sh_aw2[t] = aw2[t];
    __syncthreads();

    // ---- P1: B' = Bm + diag(q).W4 (fp32 weights, no unpack), shared across batches ----
    for (int slot = t; slot < 640; slot += 256) {
        int j = slot * 8;
        int lane8 = slot & 63, ks = (slot >> 6) & 1;
        int kk = ks * 32 + (lane8 >> 4) * 8;
        float4 bm0 = *(const float4*)&Bmf32[j];
        float4 bm1 = *(const float4*)&Bmf32[j + 4];
        float4 w40 = *(const float4*)&W4f32[j];
        float4 w41 = *(const float4*)&W4f32[j + 4];
        #pragma unroll
        for (int bb2 = 0; bb2 < 2; ++bb2) {
            float4 qa = *(const float4*)&sh_q[bb2][kk];
            float4 qb = *(const float4*)&sh_q[bb2][kk + 4];
            uint4 res;
            res.x = pk2(bm0.x + qa.x * w40.x, bm0.y + qa.y * w40.y);
            res.y = pk2(bm0.z + qa.z * w40.z, bm0.w + qa.w * w40.w);
            res.z = pk2(bm1.x + qb.x * w41.x, bm1.y + qb.y * w41.y);
            res.w = pk2(bm1.z + qb.z * w41.z, bm1.w + qb.w * w41.w);
            *(uint4*)&sh_Bq[bb2][j] = res;
        }
    }
    // bias[b][j] = ab1[j] + q.(W1+W3)[:,j]  (fp32 exact)
    if (t < 160) {
        int bi = t >= 80;
        int j = t - bi * 80;
        float acc = ab1[j];
        const float4* aw = (const float4*)&Awt[j * 64];
        #pragma unroll
        for (int k4 = 0; k4 < 16; ++k4) {
            float4 a = aw[k4];
            float4 q = *(const float4*)&sh_q[bi][k4 * 4];
            acc += a.x * q.x + a.y * q.y + a.z * q.z + a.w * q.w;
        }
        sh_bias[bi][j] = acc;
    }
    __syncthreads();

    // ---- preload per-lane bias/aw2 rows ----
    float4 a2v[5], bv[5];
    #pragma unroll
    for (int jt = 0; jt < 5; ++jt) {
        a2v[jt] = *(const float4*)&sh_aw2[jt * 16 + quad * 4];
        bv[jt]  = *(const float4*)&sh_bias[bb][jt * 16 + quad * 4];
    }

    // ---- pack h MFMA frags (bf16) from fp32 gathers ----
    bf16x8 hi0, hc0, hi1, hc1;
    {
        unsigned* p;
        p = (unsigned*)&hi0;
        p[0] = pk2(fi[0][0].x, fi[0][0].y); p[1] = pk2(fi[0][0].z, fi[0][0].w);
        p[2] = pk2(fi[0][1].x, fi[0][1].y); p[3] = pk2(fi[0][1].z, fi[0][1].w);
        p = (unsigned*)&hc0;
        p[0] = pk2(fc[0][0].x, fc[0][0].y); p[1] = pk2(fc[0][0].z, fc[0][0].w);
        p[2] = pk2(fc[0][1].x, fc[0][1].y); p[3] = pk2(fc[0][1].z, fc[0][1].w);
        p = (unsigned*)&hi1;
        p[0] = pk2(fi[1][0].x, fi[1][0].y); p[1] = pk2(fi[1][0].z, fi[1][0].w);
        p[2] = pk2(fi[1][1].x, fi[1][1].y); p[3] = pk2(fi[1][1].z, fi[1][1].w);
        p = (unsigned*)&hc1;
        p[0] = pk2(fc[1][0].x, fc[1][0].y); p[1] = pk2(fc[1][0].z, fc[1][0].w);
        p[2] = pk2(fc[1][1].x, fc[1][1].y); p[3] = pk2(fc[1][1].z, fc[1][1].w);
    }

    // ---- P2: transposed MFMA  D[j][l] = sum_d B'[d][j] * h[l][d] ----
    float px = 0.f, py = 0.f;
    #pragma unroll
    for (int jt = 0; jt < 5; ++jt) {
        f32x4 a0 = (f32x4){0.f, 0.f, 0.f, 0.f};
        f32x4 a1 = (f32x4){0.f, 0.f, 0.f, 0.f};
        bf16x8 A0 = *(const bf16x8*)&sh_Bq[bb][((jt * 2 + 0) * 64 + lane) * 8];
        bf16x8 A1 = *(const bf16x8*)&sh_Bq[bb][((jt * 2 + 1) * 64 + lane) * 8];
        a0 = __builtin_amdgcn_mfma_f32_16x16x32_bf16(A0, hi0, a0, 0, 0, 0);
        a0 = __builtin_amdgcn_mfma_f32_16x16x32_bf16(A1, hc0, a0, 0, 0, 0);
        a1 = __builtin_amdgcn_mfma_f32_16x16x32_bf16(A0, hi1, a1, 0, 0, 0);
        a1 = __builtin_amdgcn_mfma_f32_16x16x32_bf16(A1, hc1, a1, 0, 0, 0);
        const float* bp = (const float*)&bv[jt];
        const float* ap = (const float*)&a2v[jt];
        #pragma unroll
        for (int i = 0; i < 4; ++i) {
            px += fmaxf(a0[i] + bp[i], 0.f) * ap[i];
            py += fmaxf(a1[i] + bp[i], 0.f) * ap[i];
        }
    }
    px += __shfl_xor(px, 16); px += __shfl_xor(px, 32);
    py += __shfl_xor(py, 16); py += __shfl_xor(py, 32);
    if (quad == 0) {
        sh_sc[bb][hwv * 32 + col] = px;
        sh_sc[bb][hwv * 32 + 16 + col] = py;
    }
    __syncthreads();

    // ---- softmax (wave-local) ----
    float sc = -INFINITY;
    if (lane < LHIST) {
        sc = sh_sc[bb][lane];
        if (hg[b * LHIST + lane] == 0) sc = -1e9f;
    }
    float m = sc;
    #pragma unroll
    for (int off = 32; off > 0; off >>= 1) m = fmaxf(m, __shfl_xor(m, off));
    float e = (lane < LHIST) ? __expf(sc - m) : 0.f;
    float ssum = e;
    #pragma unroll
    for (int off = 32; off > 0; off >>= 1) ssum += __shfl_xor(ssum, off);
    float w = e / ssum;    // 0 for lane >= LHIST

    // ---- att: fp32 h partials, LDS transpose-reduce (reuse sh_Bq, dead now) ----
    {
        float wl0 = __shfl(w, hwv * 32 + col);
        float wl1 = __shfl(w, hwv * 32 + 16 + col);
        const float* f00 = (const float*)&fi[0][0];
        const float* f10 = (const float*)&fi[1][0];
        const float* c00 = (const float*)&fc[0][0];
        const float* c10 = (const float*)&fc[1][0];
        float ati[8], atc[8];
        #pragma unroll
        for (int j = 0; j < 8; ++j) {
            ati[j] = wl0 * f00[j] + wl1 * f10[j];
            atc[j] = wl0 * c00[j] + wl1 * c10[j];
        }
        float* red = (float*)sh_Bq;                    // 5120 floats; need 4*1056
        float* myrow = red + wv * 1056 + col * 66;
        #pragma unroll
        for (int j2 = 0; j2 < 4; ++j2) {
            *(float2*)&myrow[quad * 8 + j2 * 2]      = make_float2(ati[2 * j2], ati[2 * j2 + 1]);
            *(float2*)&myrow[33 + quad * 8 + j2 * 2] = make_float2(atc[2 * j2], atc[2 * j2 + 1]);
        }
        int colIdx = (lane < 32) ? lane : 33 + (lane - 32);
        float s = 0.f;
        #pragma unroll
        for (int c = 0; c < 16; ++c) s += red[wv * 1056 + c * 66 + colIdx];
        sh_att[wv][lane] = s;                          // d = lane
    }
    __syncthreads();

    // ---- write combined (coalesced fp32) ----
    if (wv < 2) {
        int bo = b0 + wv;
        float* crow = combined + (size_t)bo * 160;
        crow[32 + lane] = sh_q[wv][lane];
        crow[96 + lane] = sh_att[2 * wv][lane] + sh_att[2 * wv + 1][lane];
        if (lane < 32) crow[lane] = user_table[(size_t)cid[bo] * 32 + lane];
    }
}

// ---------- MLP: MFMA, 32 batch rows per 256-thread block ----------
__global__ void __launch_bounds__(256, 4) mlp_kernel(
    const float* __restrict__ combined,
    const unsigned short* __restrict__ W1f, const unsigned short* __restrict__ W2f,
    const float* __restrict__ mb1, const float* __restrict__ mb2,
    const float* __restrict__ mw3, const float* __restrict__ mb3,
    float* __restrict__ out)
{
    __shared__ __align__(16) unsigned short shA1[5120];   // [mt2][ks5][lane][8]
    __shared__ __align__(16) unsigned short shA2[8192];   // [mt2][ks8][lane][8]
    __shared__ float sh_part[4][32];

    const int t = threadIdx.x;
    const int b0 = blockIdx.x * 32;
    const int wv = t >> 6;
    const int lane = t & 63;
    const int quad = lane >> 4;
    const int col = lane & 15;

    for (int i = t; i < 1280; i += 256) {
        int m = i / 40;
        int s = i - m * 40;
        int k0 = s * 4;
        float4 v = *(const float4*)&combined[(size_t)(b0 + m) * 160 + k0];
        int mt = m >> 4, colm = m & 15;
        int ks = k0 >> 5, qd = (k0 >> 3) & 3, off = k0 & 7;
        ushort4 r; r.x = f2bf(v.x); r.y = f2bf(v.y); r.z = f2bf(v.z); r.w = f2bf(v.w);
        *(ushort4*)&shA1[((mt * 5 + ks) * 64 + qd * 16 + colm) * 8 + off] = r;
    }
    __syncthreads();

    f32x4 acc1[2][4];
    #pragma unroll
    for (int mt = 0; mt < 2; ++mt)
        #pragma unroll
        for (int j = 0; j < 4; ++j) acc1[mt][j] = (f32x4){0.f, 0.f, 0.f, 0.f};
    #pragma unroll
    for (int ks = 0; ks < 5; ++ks) {
        bf16x8 a0 = *(const bf16x8*)&shA1[(ks * 64 + lane) * 8];
        bf16x8 a1 = *(const bf16x8*)&shA1[((5 + ks) * 64 + lane) * 8];
        #pragma unroll
        for (int j = 0; j < 4; ++j) {
            int ntg = wv * 4 + j;
            bf16x8 bw = *(const bf16x8*)&W1f[((ntg * 5 + ks) * 64 + lane) * 8];
            acc1[0][j] = __builtin_amdgcn_mfma_f32_16x16x32_bf16(a0, bw, acc1[0][j], 0, 0, 0);
            acc1[1][j] = __builtin_amdgcn_mfma_f32_16x16x32_bf16(a1, bw, acc1[1][j], 0, 0, 0);
        }
    }
    #pragma unroll
    for (int j = 0; j < 4; ++j) {
        int n = (wv * 4 + j) * 16 + col;
        float bj = mb1[n];
        int ks2 = n >> 5, qd2 = (n >> 3) & 3, off2 = n & 7;
        #pragma unroll
        for (int mt = 0; mt < 2; ++mt)
            #pragma unroll
            for (int i = 0; i < 4; ++i) {
                float z = fmaxf(acc1[mt][j][i] + bj, 0.f);
                shA2[((mt * 8 + ks2) * 64 + qd2 * 16 + quad * 4 + i) * 8 + off2] = f2bf(z);
            }
    }
    __syncthreads();

    f32x4 acc2[2][2];
    #pragma unroll
    for (int mt = 0; mt < 2; ++mt)
        #pragma unroll
        for (int jj = 0; jj < 2; ++jj) acc2[mt][jj] = (f32x4){0.f, 0.f, 0.f, 0.f};
    #pragma unroll
    for (int ks = 0; ks < 8; ++ks) {
        bf16x8 a0 = *(const bf16x8*)&shA2[(ks * 64 + lane) * 8];
        bf16x8 a1 = *(const bf16x8*)&shA2[((8 + ks) * 64 + lane) * 8];
        #pragma unroll
        for (int jj = 0; jj < 2; ++jj) {
            int ntg = wv * 2 + jj;
            bf16x8 bw = *(const bf16x8*)&W2f[((ntg * 8 + ks) * 64 + lane) * 8];
            acc2[0][jj] = __builtin_amdgcn_mfma_f32_16x16x32_bf16(a0, bw, acc2[0][jj], 0, 0, 0);
            acc2[1][jj] = __builtin_amdgcn_mfma_f32_16x16x32_bf16(a1, bw, acc2[1][jj], 0, 0, 0);
        }
    }
    #pragma unroll
    for (int mt = 0; mt < 2; ++mt) {
        #pragma unroll
        for (int i = 0; i < 4; ++i) {
            float p = 0.f;
            #pragma unroll
            for (int jj = 0; jj < 2; ++jj) {
                int n = (wv * 2 + jj) * 16 + col;
                float z = fmaxf(acc2[mt][jj][i] + mb2[n], 0.f);
                p += z * mw3[n];
            }
            p += __shfl_xor(p, 1);
            p += __shfl_xor(p, 2);
            p += __shfl_xor(p, 4);
            p += __shfl_xor(p, 8);
            if (col == 0) sh_part[wv][mt * 16 + quad * 4 + i] = p;
        }
    }
    __syncthreads();
    if (t < 32)
        out[b0 + t] = sh_part[0][t] + sh_part[1][t] + sh_part[2][t] + sh_part[3][t] + mb3[0];
}

extern "C" void kernel_launch(void* const* d_in, const int* in_sizes, int n_in,
                              void* d_out, int out_size, void* d_ws, size_t ws_size,
                              hipStream_t stream) {
    const int*   cid = (const int*)d_in[0];
    const int*   cg  = (const int*)d_in[1];
    const int*   cc  = (const int*)d_in[2];
    const int*   hg  = (const int*)d_in[3];
    const int*   hc  = (const int*)d_in[4];
    const float* user_table = (const float*)d_in[5];
    const float* item_table = (const float*)d_in[6];
    const float* cat_table  = (const float*)d_in[7];
    const float* aw1 = (const float*)d_in[8];
    const float* ab1 = (const float*)d_in[9];
    const float* aw2 = (const float*)d_in[10];
    const float* mw1 = (const float*)d_in[12];
    const float* mb1 = (const float*)d_in[13];
    const float* mw2 = (const float*)d_in[14];
    const float* mb2 = (const float*)d_in[15];
    const float* mw3 = (const float*)d_in[16];
    const float* mb3 = (const float*)d_in[17];
    float* out = (float*)d_out;

    const int B = in_sizes[0];                    // 16384
    float* ws = (float*)d_ws;
    float* Awt   = ws;
    float* Bmf32 = ws + 5120;
    float* W4f32 = ws + 10240;
    unsigned short* W1f = (unsigned short*)(ws + 15360);
    unsigned short* W2f = (unsigned short*)(ws + 35840);
    float* combined = ws + 52224;

    prep_kernel<<<160, 256, 0, stream>>>(aw1, mw1, mw2, Awt, Bmf32, W4f32, W1f, W2f);
    attn_kernel<<<B / 2, 256, 0, stream>>>(cid, cg, cc, hg, hc,
                                           user_table, item_table, cat_table,
                                           ab1, aw2, Awt, Bmf32, W4f32, combined);
    mlp_kernel<<<B / 32, 256, 0, stream>>>(combined, W1f, W2f,
                                           mb1, mb2, mw3, mb3, out);
}

// Round 12
// 189.456 us; speedup vs baseline: 1.3157x; 1.3157x over previous
//
#include <hip/hip_runtime.h>
#include <hip/hip_bf16.h>
#include <math.h>

#define LHIST 50

typedef __attribute__((ext_vector_type(8))) short bf16x8;
typedef __attribute__((ext_vector_type(4))) float f32x4;

__device__ __forceinline__ unsigned short f2bf(float f) {
    union { float f; unsigned u; } v; v.f = f;
    unsigned r = v.u + 0x7fff + ((v.u >> 16) & 1);   // RNE
    return (unsigned short)(r >> 16);
}
__device__ __forceinline__ float bf2f(unsigned short h) {
    union { unsigned u; float f; } v; v.u = ((unsigned)h) << 16;
    return v.f;
}
__device__ __forceinline__ unsigned pk2(float lo, float hi) {   // v_cvt_pk_bf16_f32
    __hip_bfloat162 h = __float22bfloat162_rn(make_float2(lo, hi));
    return *(unsigned*)&h;
}

// ws float offsets:
//  Awt    [80][64] fp32                   @ 0         (5120)
//  Bmf32  frag fp32 [nt5][ks2][lane][8]   @ 5120      (5120)
//  W4f32  frag fp32 [nt5][ks2][lane][8]   @ 10240     (5120)
//  W1f    frag bf16 [nt16][ks5][lane][8]  @ 15360     (20480 f)
//  W2f    frag bf16 [nt8][ks8][lane][8]   @ 35840     (16384 f)
//  itemb  bf16 [NI*32]                    @ 52224     (NI*16 f)
//  catb   bf16 [NC*32]                    after itemb
//  combined [B][160] fp32                 after catb

__global__ void prep_kernel(const float* __restrict__ aw1,
                            const float* __restrict__ mw1,
                            const float* __restrict__ mw2,
                            const float* __restrict__ item_table,
                            const float* __restrict__ cat_table,
                            int itemN, int catN,
                            float* __restrict__ Awt,
                            float* __restrict__ Bmf32,
                            float* __restrict__ W4f32,
                            unsigned short* __restrict__ W1f,
                            unsigned short* __restrict__ W2f,
                            unsigned short* __restrict__ itemb,
                            unsigned short* __restrict__ catb) {
    int i = blockIdx.x * 256 + threadIdx.x;
    int i8 = i * 8;
    if (i8 + 7 < itemN) {
        float4 a = *(const float4*)&item_table[i8];
        float4 b = *(const float4*)&item_table[i8 + 4];
        uint4 r;
        r.x = pk2(a.x, a.y); r.y = pk2(a.z, a.w);
        r.z = pk2(b.x, b.y); r.w = pk2(b.z, b.w);
        *(uint4*)&itemb[i8] = r;
    }
    if (i8 + 7 < catN) {
        float4 a = *(const float4*)&cat_table[i8];
        float4 b = *(const float4*)&cat_table[i8 + 4];
        uint4 r;
        r.x = pk2(a.x, a.y); r.y = pk2(a.z, a.w);
        r.z = pk2(b.x, b.y); r.w = pk2(b.z, b.w);
        *(uint4*)&catb[i8] = r;
    }
    if (i < 5120) {
        int j = i >> 6, k = i & 63;
        Awt[i] = aw1[k * 80 + j] + aw1[(128 + k) * 80 + j];     // (W1+W3)^T
        int kk = i / 80, n = i - kk * 80;
        int nt = n >> 4, colw = n & 15, ks = kk >> 5, r = kk & 31, qd = r >> 3, off = r & 7;
        int d = ((nt * 2 + ks) * 64 + qd * 16 + colw) * 8 + off;
        Bmf32[d] = aw1[(64 + kk) * 80 + n] - aw1[(128 + kk) * 80 + n];  // W2-W3
        W4f32[d] = aw1[(192 + kk) * 80 + n];
    }
    if (i < 40960) {
        int kk = i >> 8, n = i & 255;
        int nt = n >> 4, colw = n & 15, ks = kk >> 5, r = kk & 31, qd = r >> 3, off = r & 7;
        W1f[((nt * 5 + ks) * 64 + qd * 16 + colw) * 8 + off] = f2bf(mw1[i]);
    }
    if (i < 32768) {
        int kk = i >> 7, n = i & 127;
        int nt = n >> 4, colw = n & 15, ks = kk >> 5, r = kk & 31, qd = r >> 3, off = r & 7;
        W2f[((nt * 8 + ks) * 64 + qd * 16 + colw) * 8 + off] = f2bf(mw2[i]);
    }
}

// ---------- attention: 2 batches/block, transposed MFMA, bf16 table gathers ----------
__global__ void __launch_bounds__(256, 6) attn_kernel(
    const int* __restrict__ cid, const int* __restrict__ cg,
    const int* __restrict__ cc,  const int* __restrict__ hg,
    const int* __restrict__ hc,
    const float* __restrict__ user_table, const float* __restrict__ item_table,
    const float* __restrict__ cat_table,
    const float* __restrict__ ab1, const float* __restrict__ aw2,
    const float* __restrict__ Awt, const float* __restrict__ Bmf32,
    const float* __restrict__ W4f32,
    const unsigned short* __restrict__ itemb, const unsigned short* __restrict__ catb,
    float* __restrict__ combined)
{
    __shared__ __align__(16) unsigned short sh_Bq[2][5120];   // [b][nt5][ks2][lane][8]; reused as att scratch
    __shared__ __align__(16) float sh_q[2][64];
    __shared__ float sh_bias[2][80];
    __shared__ float sh_sc[2][64];
    __shared__ float sh_aw2[80];
    __shared__ float sh_att[4][64];

    const int t = threadIdx.x;
    const int b0 = blockIdx.x * 2;
    const int wv = t >> 6;
    const int lane = t & 63;
    const int quad = lane >> 4;
    const int col = lane & 15;
    const int bb = wv >> 1;      // batch of this wave
    const int hwv = wv & 1;      // half of l-range
    const int b = b0 + bb;

    // ---- P0: history indices + bf16 gathers issued immediately ----
    int il[2], ic[2];
    #pragma unroll
    for (int mi = 0; mi < 2; ++mi) {
        int l = hwv * 32 + mi * 16 + col;
        int lc = (l < LHIST) ? l : 0;
        il[mi] = hg[b * LHIST + lc];
        ic[mi] = hc[b * LHIST + lc];
    }
    uint4 vi[2], vc[2];
    #pragma unroll
    for (int mi = 0; mi < 2; ++mi) {
        vi[mi] = *(const uint4*)&itemb[(size_t)il[mi] * 32 + quad * 8];
        vc[mi] = *(const uint4*)&catb[(size_t)ic[mi] * 32 + quad * 8];
    }
    if (t < 128) {
        int qbi = t >> 6, k = t & 63;
        int bq = b0 + qbi;
        float v = (k < 32) ? item_table[(size_t)cg[bq] * 32 + k]
                           : cat_table[(size_t)cc[bq] * 32 + (k - 32)];
        sh_q[qbi][k] = v;
    }
    if (t < 80) sh_aw2[t] = aw2[t];
    __syncthreads();

    // ---- P1: B' = Bm + diag(q).W4 (fp32 frag weights, no unpack), shared across batches ----
    for (int slot = t; slot < 640; slot += 256) {
        int j = slot * 8;
        int lane8 = slot & 63, ks = (slot >> 6) & 1;
        int kk = ks * 32 + (lane8 >> 4) * 8;
        float4 bm0 = *(const float4*)&Bmf32[j];
        float4 bm1 = *(const float4*)&Bmf32[j + 4];
        float4 w40 = *(const float4*)&W4f32[j];
        float4 w41 = *(const float4*)&W4f32[j + 4];
        #pragma unroll
        for (int bb2 = 0; bb2 < 2; ++bb2) {
            float4 qa = *(const float4*)&sh_q[bb2][kk];
            float4 qb = *(const float4*)&sh_q[bb2][kk + 4];
            uint4 res;
            res.x = pk2(bm0.x + qa.x * w40.x, bm0.y + qa.y * w40.y);
            res.y = pk2(bm0.z + qa.z * w40.z, bm0.w + qa.w * w40.w);
            res.z = pk2(bm1.x + qb.x * w41.x, bm1.y + qb.y * w41.y);
            res.w = pk2(bm1.z + qb.z * w41.z, bm1.w + qb.w * w41.w);
            *(uint4*)&sh_Bq[bb2][j] = res;
        }
    }
    // bias[b][j] = ab1[j] + q.(W1+W3)[:,j]  (fp32 exact)
    if (t < 160) {
        int bi = t >= 80;
        int j = t - bi * 80;
        float acc = ab1[j];
        const float4* aw = (const float4*)&Awt[j * 64];
        #pragma unroll
        for (int k4 = 0; k4 < 16; ++k4) {
            float4 a = aw[k4];
            float4 q = *(const float4*)&sh_q[bi][k4 * 4];
            acc += a.x * q.x + a.y * q.y + a.z * q.z + a.w * q.w;
        }
        sh_bias[bi][j] = acc;
    }
    __syncthreads();

    // ---- preload per-lane bias/aw2 rows ----
    float4 a2v[5], bv[5];
    #pragma unroll
    for (int jt = 0; jt < 5; ++jt) {
        a2v[jt] = *(const float4*)&sh_aw2[jt * 16 + quad * 4];
        bv[jt]  = *(const float4*)&sh_bias[bb][jt * 16 + quad * 4];
    }

    // ---- P2: transposed MFMA  D[j][l] = sum_d B'[d][j] * h[l][d] ----
    bf16x8 hi0 = *(bf16x8*)&vi[0];
    bf16x8 hc0 = *(bf16x8*)&vc[0];
    bf16x8 hi1 = *(bf16x8*)&vi[1];
    bf16x8 hc1 = *(bf16x8*)&vc[1];
    float px = 0.f, py = 0.f;
    #pragma unroll
    for (int jt = 0; jt < 5; ++jt) {
        f32x4 a0 = (f32x4){0.f, 0.f, 0.f, 0.f};
        f32x4 a1 = (f32x4){0.f, 0.f, 0.f, 0.f};
        bf16x8 A0 = *(const bf16x8*)&sh_Bq[bb][((jt * 2 + 0) * 64 + lane) * 8];
        bf16x8 A1 = *(const bf16x8*)&sh_Bq[bb][((jt * 2 + 1) * 64 + lane) * 8];
        a0 = __builtin_amdgcn_mfma_f32_16x16x32_bf16(A0, hi0, a0, 0, 0, 0);
        a0 = __builtin_amdgcn_mfma_f32_16x16x32_bf16(A1, hc0, a0, 0, 0, 0);
        a1 = __builtin_amdgcn_mfma_f32_16x16x32_bf16(A0, hi1, a1, 0, 0, 0);
        a1 = __builtin_amdgcn_mfma_f32_16x16x32_bf16(A1, hc1, a1, 0, 0, 0);
        const float* bp = (const float*)&bv[jt];
        const float* ap = (const float*)&a2v[jt];
        #pragma unroll
        for (int i = 0; i < 4; ++i) {
            px += fmaxf(a0[i] + bp[i], 0.f) * ap[i];
            py += fmaxf(a1[i] + bp[i], 0.f) * ap[i];
        }
    }
    px += __shfl_xor(px, 16); px += __shfl_xor(px, 32);
    py += __shfl_xor(py, 16); py += __shfl_xor(py, 32);
    if (quad == 0) {
        sh_sc[bb][hwv * 32 + col] = px;
        sh_sc[bb][hwv * 32 + 16 + col] = py;
    }
    __syncthreads();

    // ---- softmax (wave-local) ----
    float sc = -INFINITY;
    if (lane < LHIST) {
        sc = sh_sc[bb][lane];
        if (hg[b * LHIST + lane] == 0) sc = -1e9f;
    }
    float m = sc;
    #pragma unroll
    for (int off = 32; off > 0; off >>= 1) m = fmaxf(m, __shfl_xor(m, off));
    float e = (lane < LHIST) ? __expf(sc - m) : 0.f;
    float ssum = e;
    #pragma unroll
    for (int off = 32; off > 0; off >>= 1) ssum += __shfl_xor(ssum, off);
    float w = e / ssum;    // 0 for lane >= LHIST

    // ---- att: per-lane partials, LDS transpose-reduce (reuse sh_Bq, dead now) ----
    {
        float wl0 = __shfl(w, hwv * 32 + col);
        float wl1 = __shfl(w, hwv * 32 + 16 + col);
        union { uint4 u; unsigned short s[8]; } i0, i1, c0u, c1u;
        i0.u = vi[0]; i1.u = vi[1]; c0u.u = vc[0]; c1u.u = vc[1];
        float ati[8], atc[8];
        #pragma unroll
        for (int j = 0; j < 8; ++j) {
            ati[j] = wl0 * bf2f(i0.s[j]) + wl1 * bf2f(i1.s[j]);
            atc[j] = wl0 * bf2f(c0u.s[j]) + wl1 * bf2f(c1u.s[j]);
        }
        float* red = (float*)sh_Bq;                    // 5120 floats; need 4*1056
        float* myrow = red + wv * 1056 + col * 66;
        #pragma unroll
        for (int j2 = 0; j2 < 4; ++j2) {
            *(float2*)&myrow[quad * 8 + j2 * 2]      = make_float2(ati[2 * j2], ati[2 * j2 + 1]);
            *(float2*)&myrow[33 + quad * 8 + j2 * 2] = make_float2(atc[2 * j2], atc[2 * j2 + 1]);
        }
        int colIdx = (lane < 32) ? lane : 33 + (lane - 32);
        float s = 0.f;
        #pragma unroll
        for (int c = 0; c < 16; ++c) s += red[wv * 1056 + c * 66 + colIdx];
        sh_att[wv][lane] = s;                          // d = lane
    }
    __syncthreads();

    // ---- write combined (coalesced fp32) ----
    if (wv < 2) {
        int bo = b0 + wv;
        float* crow = combined + (size_t)bo * 160;
        crow[32 + lane] = sh_q[wv][lane];
        crow[96 + lane] = sh_att[2 * wv][lane] + sh_att[2 * wv + 1][lane];
        if (lane < 32) crow[lane] = user_table[(size_t)cid[bo] * 32 + lane];
    }
}

// ---------- MLP: MFMA, 32 batch rows per 256-thread block ----------
__global__ void __launch_bounds__(256, 4) mlp_kernel(
    const float* __restrict__ combined,
    const unsigned short* __restrict__ W1f, const unsigned short* __restrict__ W2f,
    const float* __restrict__ mb1, const float* __restrict__ mb2,
    const float* __restrict__ mw3, const float* __restrict__ mb3,
    float* __restrict__ out)
{
    __shared__ __align__(16) unsigned short shA1[5120];   // [mt2][ks5][lane][8]
    __shared__ __align__(16) unsigned short shA2[8192];   // [mt2][ks8][lane][8]
    __shared__ float sh_part[4][32];

    const int t = threadIdx.x;
    const int b0 = blockIdx.x * 32;
    const int wv = t >> 6;
    const int lane = t & 63;
    const int quad = lane >> 4;
    const int col = lane & 15;

    for (int i = t; i < 1280; i += 256) {
        int m = i / 40;
        int s = i - m * 40;
        int k0 = s * 4;
        float4 v = *(const float4*)&combined[(size_t)(b0 + m) * 160 + k0];
        int mt = m >> 4, colm = m & 15;
        int ks = k0 >> 5, qd = (k0 >> 3) & 3, off = k0 & 7;
        ushort4 r; r.x = f2bf(v.x); r.y = f2bf(v.y); r.z = f2bf(v.z); r.w = f2bf(v.w);
        *(ushort4*)&shA1[((mt * 5 + ks) * 64 + qd * 16 + colm) * 8 + off] = r;
    }
    __syncthreads();

    f32x4 acc1[2][4];
    #pragma unroll
    for (int mt = 0; mt < 2; ++mt)
        #pragma unroll
        for (int j = 0; j < 4; ++j) acc1[mt][j] = (f32x4){0.f, 0.f, 0.f, 0.f};
    #pragma unroll
    for (int ks = 0; ks < 5; ++ks) {
        bf16x8 a0 = *(const bf16x8*)&shA1[(ks * 64 + lane) * 8];
        bf16x8 a1 = *(const bf16x8*)&shA1[((5 + ks) * 64 + lane) * 8];
        #pragma unroll
        for (int j = 0; j < 4; ++j) {
            int ntg = wv * 4 + j;
            bf16x8 bw = *(const bf16x8*)&W1f[((ntg * 5 + ks) * 64 + lane) * 8];
            acc1[0][j] = __builtin_amdgcn_mfma_f32_16x16x32_bf16(a0, bw, acc1[0][j], 0, 0, 0);
            acc1[1][j] = __builtin_amdgcn_mfma_f32_16x16x32_bf16(a1, bw, acc1[1][j], 0, 0, 0);
        }
    }
    #pragma unroll
    for (int j = 0; j < 4; ++j) {
        int n = (wv * 4 + j) * 16 + col;
        float bj = mb1[n];
        int ks2 = n >> 5, qd2 = (n >> 3) & 3, off2 = n & 7;
        #pragma unroll
        for (int mt = 0; mt < 2; ++mt)
            #pragma unroll
            for (int i = 0; i < 4; ++i) {
                float z = fmaxf(acc1[mt][j][i] + bj, 0.f);
                shA2[((mt * 8 + ks2) * 64 + qd2 * 16 + quad * 4 + i) * 8 + off2] = f2bf(z);
            }
    }
    __syncthreads();

    f32x4 acc2[2][2];
    #pragma unroll
    for (int mt = 0; mt < 2; ++mt)
        #pragma unroll
        for (int jj = 0; jj < 2; ++jj) acc2[mt][jj] = (f32x4){0.f, 0.f, 0.f, 0.f};
    #pragma unroll
    for (int ks = 0; ks < 8; ++ks) {
        bf16x8 a0 = *(const bf16x8*)&shA2[(ks * 64 + lane) * 8];
        bf16x8 a1 = *(const bf16x8*)&shA2[((8 + ks) * 64 + lane) * 8];
        #pragma unroll
        for (int jj = 0; jj < 2; ++jj) {
            int ntg = wv * 2 + jj;
            bf16x8 bw = *(const bf16x8*)&W2f[((ntg * 8 + ks) * 64 + lane) * 8];
            acc2[0][jj] = __builtin_amdgcn_mfma_f32_16x16x32_bf16(a0, bw, acc2[0][jj], 0, 0, 0);
            acc2[1][jj] = __builtin_amdgcn_mfma_f32_16x16x32_bf16(a1, bw, acc2[1][jj], 0, 0, 0);
        }
    }
    #pragma unroll
    for (int mt = 0; mt < 2; ++mt) {
        #pragma unroll
        for (int i = 0; i < 4; ++i) {
            float p = 0.f;
            #pragma unroll
            for (int jj = 0; jj < 2; ++jj) {
                int n = (wv * 2 + jj) * 16 + col;
                float z = fmaxf(acc2[mt][jj][i] + mb2[n], 0.f);
                p += z * mw3[n];
            }
            p += __shfl_xor(p, 1);
            p += __shfl_xor(p, 2);
            p += __shfl_xor(p, 4);
            p += __shfl_xor(p, 8);
            if (col == 0) sh_part[wv][mt * 16 + quad * 4 + i] = p;
        }
    }
    __syncthreads();
    if (t < 32)
        out[b0 + t] = sh_part[0][t] + sh_part[1][t] + sh_part[2][t] + sh_part[3][t] + mb3[0];
}

extern "C" void kernel_launch(void* const* d_in, const int* in_sizes, int n_in,
                              void* d_out, int out_size, void* d_ws, size_t ws_size,
                              hipStream_t stream) {
    const int*   cid = (const int*)d_in[0];
    const int*   cg  = (const int*)d_in[1];
    const int*   cc  = (const int*)d_in[2];
    const int*   hg  = (const int*)d_in[3];
    const int*   hc  = (const int*)d_in[4];
    const float* user_table = (const float*)d_in[5];
    const float* item_table = (const float*)d_in[6];
    const float* cat_table  = (const float*)d_in[7];
    const float* aw1 = (const float*)d_in[8];
    const float* ab1 = (const float*)d_in[9];
    const float* aw2 = (const float*)d_in[10];
    const float* mw1 = (const float*)d_in[12];
    const float* mb1 = (const float*)d_in[13];
    const float* mw2 = (const float*)d_in[14];
    const float* mb2 = (const float*)d_in[15];
    const float* mw3 = (const float*)d_in[16];
    const float* mb3 = (const float*)d_in[17];
    float* out = (float*)d_out;

    const int B = in_sizes[0];                    // 16384
    const int itemN = in_sizes[6];                // NI*32
    const int catN  = in_sizes[7];                // NC*32
    float* ws = (float*)d_ws;
    float* Awt   = ws;
    float* Bmf32 = ws + 5120;
    float* W4f32 = ws + 10240;
    unsigned short* W1f = (unsigned short*)(ws + 15360);
    unsigned short* W2f = (unsigned short*)(ws + 35840);
    unsigned short* itemb = (unsigned short*)(ws + 52224);
    unsigned short* catb  = itemb + itemN;
    float* combined = ws + 52224 + (itemN + catN + 1) / 2;

    int n8 = (itemN + 7) / 8;
    int prep_grid = (n8 + 255) / 256;
    if (prep_grid < 160) prep_grid = 160;
    prep_kernel<<<prep_grid, 256, 0, stream>>>(aw1, mw1, mw2, item_table, cat_table,
                                               itemN, catN, Awt, Bmf32, W4f32, W1f, W2f,
                                               itemb, catb);
    attn_kernel<<<B / 2, 256, 0, stream>>>(cid, cg, cc, hg, hc,
                                           user_table, item_table, cat_table,
                                           ab1, aw2, Awt, Bmf32, W4f32, itemb, catb, combined);
    mlp_kernel<<<B / 32, 256, 0, stream>>>(combined, W1f, W2f,
                                           mb1, mb2, mw3, mb3, out);
}